// Round 1
// baseline (157.226 us; speedup 1.0000x reference)
//
#include <hip/hip_runtime.h>
#include <math.h>

#define BATCH 64
#define NUM_TRAJ 128
#define NTOT (BATCH*NUM_TRAJ)
#define NSTEPS 255

static constexpr float DT = 0.00390625f; // 2^-8

// One thread per trajectory. State: rho (4x4 complex) in registers.
// H = Omega*HX + eps*HZ (real symmetric sparse), C1=diag(1,1,-1,-1), C2=diag(1,-1,1,-1).
// Update: rho' = rho + dt*(-i*comm) + (W_ij - i*u)*rho_ij
//   W_ij = dt*Gamma*d_ij + (pAB_i + pAB_j) - Re(u),  u = t1*dwA + t2*dwB (complex)
//   pAB_i = s1_i*dwA + s2_i*dwB, d_ij = s1_i s1_j + s2_i s2_j - 2
__global__ __launch_bounds__(64) void traj_kernel(
    const float* __restrict__ inputs,
    const float* __restrict__ params,
    const float* __restrict__ wvec,
    const float* __restrict__ rho0,
    int rho0_cplx,
    float* __restrict__ ws)
{
    const int n = blockIdx.x * 64 + threadIdx.x;
    if (n >= NTOT) return;
    const int b = n & (BATCH - 1);

    const float Omega = inputs[b] + 1e-8f;
    const float a     = 0.5f * Omega;
    const float eps   = params[1];
    const float Gamma = params[2];
    const float eta   = params[3];
    const float sqge  = sqrtf(fmaxf(Gamma * eta, 0.0f));
    const float gdt   = Gamma * DT;
    const float e2    = -2.0f * gdt;
    const float e4    = -4.0f * gdt;
    const float dm[4][4] = {{0.f, e2, e2, e4},
                            {e2, 0.f, e4, e2},
                            {e2, e4, 0.f, e2},
                            {e4, e2, e2, 0.f}};

    float rr[4][4], ri[4][4];
#pragma unroll
    for (int i = 0; i < 4; i++)
#pragma unroll
        for (int j = 0; j < 4; j++) {
            const int idx = i * 4 + j;
            if (rho0_cplx) { rr[i][j] = rho0[2 * idx]; ri[i][j] = rho0[2 * idx + 1]; }
            else           { rr[i][j] = rho0[idx];     ri[i][j] = 0.0f; }
        }

    const float* wp = wvec + (size_t)n * (2 * NSTEPS);

    for (int t = 0; t < NSTEPS; ++t) {
        const float2 dw = *reinterpret_cast<const float2*>(wp + 2 * t);
        const float dwA = sqge * dw.x;
        const float dwB = sqge * dw.y;

        float cr[4][4], ci[4][4]; // will hold comm = H rho - rho H

        // H rho  (row structure: r0 = eps*rho0 + a*(rho1+rho2); r1=r2=a*(rho0+rho3);
        //         r3 = a*(rho1+rho2) - eps*rho3)
#pragma unroll
        for (int j = 0; j < 4; j++) {
            const float s1r = rr[1][j] + rr[2][j], s1i = ri[1][j] + ri[2][j];
            const float s0r = rr[0][j] + rr[3][j], s0i = ri[0][j] + ri[3][j];
            const float a1r = a * s1r, a1i = a * s1i;
            const float a0r = a * s0r, a0i = a * s0i;
            cr[0][j] = fmaf(eps, rr[0][j], a1r);  ci[0][j] = fmaf(eps, ri[0][j], a1i);
            cr[1][j] = a0r;                       ci[1][j] = a0i;
            cr[2][j] = a0r;                       ci[2][j] = a0i;
            cr[3][j] = fmaf(-eps, rr[3][j], a1r); ci[3][j] = fmaf(-eps, ri[3][j], a1i);
        }
        // subtract rho H (same structure over columns)
#pragma unroll
        for (int i = 0; i < 4; i++) {
            const float u1r = rr[i][1] + rr[i][2], u1i = ri[i][1] + ri[i][2];
            const float u0r = rr[i][0] + rr[i][3], u0i = ri[i][0] + ri[i][3];
            const float b1r = a * u1r, b1i = a * u1i;
            const float b0r = a * u0r, b0i = a * u0i;
            cr[i][0] -= fmaf(eps, rr[i][0], b1r);  ci[i][0] -= fmaf(eps, ri[i][0], b1i);
            cr[i][1] -= b0r;                       ci[i][1] -= b0i;
            cr[i][2] -= b0r;                       ci[i][2] -= b0i;
            cr[i][3] -= fmaf(-eps, rr[i][3], b1r); ci[i][3] -= fmaf(-eps, ri[i][3], b1i);
        }

        // traces of (C rho + rho C): t1 = 2(r00+r11-r22-r33), t2 = 2(r00-r11+r22-r33)
        const float t1r = 2.0f * ((rr[0][0] + rr[1][1]) - (rr[2][2] + rr[3][3]));
        const float t1i = 2.0f * ((ri[0][0] + ri[1][1]) - (ri[2][2] + ri[3][3]));
        const float t2r = 2.0f * ((rr[0][0] + rr[2][2]) - (rr[1][1] + rr[3][3]));
        const float t2i = 2.0f * ((ri[0][0] + ri[2][2]) - (ri[1][1] + ri[3][3]));
        const float ur = fmaf(t1r, dwA, t2r * dwB);
        const float ui = fmaf(t1i, dwA, t2i * dwB);

        float pAB[4];
        pAB[0] =  dwA + dwB;
        pAB[1] =  dwA - dwB;
        pAB[2] =  dwB - dwA;
        pAB[3] = -dwA - dwB;

#pragma unroll
        for (int i = 0; i < 4; i++) {
            const float base = pAB[i] - ur;
#pragma unroll
            for (int j = 0; j < 4; j++) {
                const float W = base + pAB[j] + dm[i][j];
                float nr = fmaf(DT, ci[i][j], rr[i][j]);
                nr = fmaf(W, rr[i][j], nr);
                nr = fmaf(ui, ri[i][j], nr);
                float ni = fmaf(-DT, cr[i][j], ri[i][j]);
                ni = fmaf(W, ri[i][j], ni);
                ni = fmaf(-ui, rr[i][j], ni);
                rr[i][j] = nr;
                ri[i][j] = ni;
            }
        }
    }

    float* o = ws + (size_t)n * 32;
#pragma unroll
    for (int i = 0; i < 4; i++)
#pragma unroll
        for (int j = 0; j < 4; j++) {
            o[i * 4 + j]      = rr[i][j];
            o[16 + i * 4 + j] = ri[i][j];
        }
}

__device__ inline void fill_proj(int p, float s, float pr[2][2], float pim[2][2])
{
    pr[0][0] = 0.5f; pr[0][1] = 0.f; pr[1][0] = 0.f; pr[1][1] = 0.5f;
    pim[0][0] = 0.f; pim[0][1] = 0.f; pim[1][0] = 0.f; pim[1][1] = 0.f;
    const float h = 0.5f * s;
    if (p == 0)      { pr[0][1] += h;  pr[1][0] += h; }   // sigma_x
    else if (p == 1) { pim[0][1] -= h; pim[1][0] += h; }  // sigma_y
    else             { pr[0][0] += h;  pr[1][1] -= h; }   // sigma_z
}

__device__ inline void fill_id(float pr[2][2], float pim[2][2])
{
    pr[0][0] = 1.f; pr[0][1] = 0.f; pr[1][0] = 0.f; pr[1][1] = 1.f;
    pim[0][0] = 0.f; pim[0][1] = 0.f; pim[1][0] = 0.f; pim[1][1] = 0.f;
}

// One block per batch element: reduce 128 trajectories -> rho_mean, compute 42
// measurement probabilities tr(M rho), clip, write [probs | input], then rho_mean.
__global__ __launch_bounds__(64) void reduce_meas_kernel(
    const float* __restrict__ ws,
    const float* __restrict__ inputs,
    float* __restrict__ out,
    int out_size)
{
    const int b = blockIdx.x;
    const int tid = threadIdx.x;
    __shared__ float sr[16], si[16];

    if (tid < 32) {
        const int plane = tid >> 4;
        const int e = tid & 15;
        float s = 0.f;
        for (int k = 0; k < NUM_TRAJ; k++)
            s += ws[((size_t)(k * BATCH + b)) * 32 + plane * 16 + e];
        s *= (1.0f / NUM_TRAJ);
        if (plane == 0) sr[e] = s; else si[e] = s;
    }
    __syncthreads();

    if (tid < 42) {
        float par[2][2], pai[2][2], pbr[2][2], pbi[2][2];
        const int m = tid;
        if (m < 36) {
            const int ia = m / 12, rem = m - ia * 12;
            const int ib = rem / 4, r2 = rem - ib * 4;
            fill_proj(ia, (r2 & 2) ? -1.f : 1.f, par, pai);
            fill_proj(ib, (r2 & 1) ? -1.f : 1.f, pbr, pbi);
        } else if (m < 39) {
            fill_proj(m - 36, 1.f, par, pai);
            fill_id(pbr, pbi);
        } else {
            fill_id(par, pai);
            fill_proj(m - 39, 1.f, pbr, pbi);
        }
        // prob = Re sum_ij M_ij rho_ji,  i=2*a1+b1, j=2*a2+b2 (kron index)
        float prob = 0.f;
#pragma unroll
        for (int a1 = 0; a1 < 2; a1++)
#pragma unroll
            for (int b1 = 0; b1 < 2; b1++)
#pragma unroll
                for (int a2 = 0; a2 < 2; a2++)
#pragma unroll
                    for (int b2 = 0; b2 < 2; b2++) {
                        const int i = 2 * a1 + b1, j = 2 * a2 + b2;
                        const float Mr = par[a1][a2] * pbr[b1][b2] - pai[a1][a2] * pbi[b1][b2];
                        const float Mi = par[a1][a2] * pbi[b1][b2] + pai[a1][a2] * pbr[b1][b2];
                        prob += Mr * sr[j * 4 + i] - Mi * si[j * 4 + i];
                    }
        prob = fminf(fmaxf(prob, 0.f), 1.f);
        out[b * 43 + m] = prob;
    } else if (tid == 42) {
        out[b * 43 + 42] = inputs[b];
    }

    // rho_mean tail: interleaved re/im (complex viewed as float pairs) if room,
    // else real part only.
    if (out_size >= 2752 + 2048) {
        if (tid < 16) {
            out[2752 + b * 32 + 2 * tid]     = sr[tid];
            out[2752 + b * 32 + 2 * tid + 1] = si[tid];
        }
    } else if (out_size >= 2752 + 1024) {
        if (tid < 16) out[2752 + b * 16 + tid] = sr[tid];
    }
}

extern "C" void kernel_launch(void* const* d_in, const int* in_sizes, int n_in,
                              void* d_out, int out_size, void* d_ws, size_t ws_size,
                              hipStream_t stream)
{
    const float* inputs = (const float*)d_in[0];
    const float* params = (const float*)d_in[1];
    const float* wvec   = (const float*)d_in[2];
    const float* rho0   = (const float*)d_in[3];
    const int rho0_cplx = (n_in > 3 && in_sizes[3] >= 32) ? 1 : 0;
    float* ws = (float*)d_ws;

    traj_kernel<<<NTOT / 64, 64, 0, stream>>>(inputs, params, wvec, rho0, rho0_cplx, ws);
    reduce_meas_kernel<<<BATCH, 64, 0, stream>>>(ws, inputs, (float*)d_out, out_size);
}

// Round 2
// 51.255 us; speedup vs baseline: 3.0675x; 3.0675x over previous
//
#include <hip/hip_runtime.h>
#include <math.h>

#define BATCH 64
#define NUM_TRAJ 128
#define NTOT (BATCH*NUM_TRAJ)
#define NSTEPS 255

static constexpr float DT = 0.00390625f; // 2^-8

// quad_perm DPP shuffle (compile-time ctrl), float
template<int C>
__device__ __forceinline__ float qp(float x) {
    union { float f; int i; } u;
    u.f = x;
    u.i = __builtin_amdgcn_update_dpp(0, u.i, C, 0xF, 0xF, true);
    return u.f;
}

// For lane (row) i, sum of the two "other" rows needed by H*rho:
// lane0,3 need rows 1+2 ; lane1,2 need rows 0+3.
// shuffleA pattern (1,0,0,1) -> ctrl 65 ; shuffleB pattern (2,3,3,2) -> ctrl 190.
__device__ __forceinline__ float qsum2(float x) {
    return qp<65>(x) + qp<190>(x);
}

// 4 lanes per trajectory, one row of rho per lane (4 complex = 8 floats).
// H = Omega*HX + eps*HZ (real symmetric sparse), C1=diag(1,1,-1,-1), C2=diag(1,-1,1,-1).
// rho' = rho + dt*(-i*comm) + (W_ij - i*u)*rho_ij
//   W_ij = dt*Gamma*d_ij + pAB_i + pAB_j - Re(u),  u = sum_i 2*pAB_i*rho_ii (complex)
//   pAB_i = s1_i*dwA + s2_i*dwB, d_ij = s1_i s1_j + s2_i s2_j - 2
__global__ __launch_bounds__(64) void traj_kernel(
    const float* __restrict__ inputs,
    const float* __restrict__ params,
    const float* __restrict__ wvec,
    const float* __restrict__ rho0,
    int rho0_cplx,
    float* __restrict__ ws)
{
    const int tid = blockIdx.x * 64 + threadIdx.x;
    const int g = tid >> 2;          // trajectory index
    const int r = tid & 3;           // row owned by this lane
    const int b = g & (BATCH - 1);

    const float Omega = inputs[b] + 1e-8f;
    const float a     = 0.5f * Omega;
    const float eps   = params[1];
    const float Gamma = params[2];
    const float eta   = params[3];
    const float sqge  = sqrtf(fmaxf(Gamma * eta, 0.0f));
    const float gdt   = Gamma * DT;

    // per-lane (row) constants
    const float s1  = (r < 2)  ? 1.0f : -1.0f;   // C1 diag
    const float s2  = (r & 1)  ? -1.0f : 1.0f;   // C2 diag
    const float dgH = (r == 0) ? eps : ((r == 3) ? -eps : 0.0f); // H diagonal
    const float e0  = dgH - eps;   // comm col0 coefficient
    const float e3  = dgH + eps;   // comm col3 coefficient
    const float dm0 = gdt * ( s1 + s2 - 2.0f);
    const float dm1 = gdt * ( s1 - s2 - 2.0f);
    const float dm2 = gdt * (-s1 + s2 - 2.0f);
    const float dm3 = gdt * (-s1 - s2 - 2.0f);
    const bool is1 = (r == 1), is2 = (r == 2), is3 = (r == 3);

    float rr[4], ri[4];
#pragma unroll
    for (int j = 0; j < 4; ++j) {
        const int idx = r * 4 + j;
        if (rho0_cplx) { rr[j] = rho0[2 * idx]; ri[j] = rho0[2 * idx + 1]; }
        else           { rr[j] = rho0[idx];     ri[j] = 0.0f; }
    }

    const float* wp = wvec + (size_t)g * (2 * NSTEPS);

    auto step = [&](float dwA, float dwB) {
        // column noise scalars
        const float p0 = dwA + dwB;
        const float p1 = dwA - dwB;
        const float p2 = -p1;
        const float p3 = -p0;
        const float pown = fmaf(s1, dwA, s2 * dwB); // pAB for own row

        // own-row column sums (for rho*H)
        const float u1r = rr[1] + rr[2], u1i = ri[1] + ri[2];
        const float u0r = rr[0] + rr[3], u0i = ri[0] + ri[3];

        // cross-row sums (for H*rho), via quad DPP
        const float s0r = qsum2(rr[0]), s0i = qsum2(ri[0]);
        const float s1r = qsum2(rr[1]), s1i = qsum2(ri[1]);
        const float s2r = qsum2(rr[2]), s2i = qsum2(ri[2]);
        const float s3r = qsum2(rr[3]), s3i = qsum2(ri[3]);

        // comm = H rho - rho H, own row
        const float c0r = fmaf(e0,  rr[0], a * (s0r - u1r));
        const float c0i = fmaf(e0,  ri[0], a * (s0i - u1i));
        const float c1r = fmaf(dgH, rr[1], a * (s1r - u0r));
        const float c1i = fmaf(dgH, ri[1], a * (s1i - u0i));
        const float c2r = fmaf(dgH, rr[2], a * (s2r - u0r));
        const float c2i = fmaf(dgH, ri[2], a * (s2i - u0i));
        const float c3r = fmaf(e3,  rr[3], a * (s3r - u1r));
        const float c3i = fmaf(e3,  ri[3], a * (s3i - u1i));

        // u = sum_i 2*pAB_i * rho_ii  (complex), quad butterfly reduce
        float dr = rr[0], di = ri[0];
        dr = is1 ? rr[1] : dr; di = is1 ? ri[1] : di;
        dr = is2 ? rr[2] : dr; di = is2 ? ri[2] : di;
        dr = is3 ? rr[3] : dr; di = is3 ? ri[3] : di;
        const float twop = pown + pown;
        float zr = twop * dr, zi = twop * di;
        zr += qp<177>(zr); zi += qp<177>(zi);   // xor 1 : quad_perm(1,0,3,2)
        zr += qp<78>(zr);  zi += qp<78>(zi);    // xor 2 : quad_perm(2,3,0,1)
        const float ur = zr, ui = zi;

        const float base = pown - ur;
        const float W0 = base + (p0 + dm0);
        const float W1 = base + (p1 + dm1);
        const float W2 = base + (p2 + dm2);
        const float W3 = base + (p3 + dm3);

        float nr, ni;
        nr = fmaf(DT, c0i, rr[0]);  nr = fmaf(W0, rr[0], nr); nr = fmaf( ui, ri[0], nr);
        ni = fmaf(-DT, c0r, ri[0]); ni = fmaf(W0, ri[0], ni); ni = fmaf(-ui, rr[0], ni);
        rr[0] = nr; ri[0] = ni;
        nr = fmaf(DT, c1i, rr[1]);  nr = fmaf(W1, rr[1], nr); nr = fmaf( ui, ri[1], nr);
        ni = fmaf(-DT, c1r, ri[1]); ni = fmaf(W1, ri[1], ni); ni = fmaf(-ui, rr[1], ni);
        rr[1] = nr; ri[1] = ni;
        nr = fmaf(DT, c2i, rr[2]);  nr = fmaf(W2, rr[2], nr); nr = fmaf( ui, ri[2], nr);
        ni = fmaf(-DT, c2r, ri[2]); ni = fmaf(W2, ri[2], ni); ni = fmaf(-ui, rr[2], ni);
        rr[2] = nr; ri[2] = ni;
        nr = fmaf(DT, c3i, rr[3]);  nr = fmaf(W3, rr[3], nr); nr = fmaf( ui, ri[3], nr);
        ni = fmaf(-DT, c3r, ri[3]); ni = fmaf(W3, ri[3], ni); ni = fmaf(-ui, rr[3], ni);
        rr[3] = nr; ri[3] = ni;
    };

    // main loop: 63 chunks of 4 steps; lane r pre-loads step (4*t4+r)'s noise,
    // broadcast within the quad per sub-step (contiguous 32B per quad).
#pragma unroll 1
    for (int t4 = 0; t4 < 63; ++t4) {
        const float2 w = *reinterpret_cast<const float2*>(wp + 2 * (t4 * 4 + r));
        const float wA = sqge * w.x, wB = sqge * w.y;
        step(qp<0>(wA),   qp<0>(wB));    // broadcast lane 0
        step(qp<85>(wA),  qp<85>(wB));   // broadcast lane 1
        step(qp<170>(wA), qp<170>(wB));  // broadcast lane 2
        step(qp<255>(wA), qp<255>(wB));  // broadcast lane 3
    }
    { // tail: steps 252..254 (clamp lane 3's load in-bounds)
        int idx = 252 + r; if (idx > 254) idx = 254;
        const float2 w = *reinterpret_cast<const float2*>(wp + 2 * idx);
        const float wA = sqge * w.x, wB = sqge * w.y;
        step(qp<0>(wA),   qp<0>(wB));
        step(qp<85>(wA),  qp<85>(wB));
        step(qp<170>(wA), qp<170>(wB));
    }

    // ws layout per trajectory: floats [0..15] = Re(rho) row-major, [16..31] = Im
    float4* o = reinterpret_cast<float4*>(ws + (size_t)g * 32);
    o[r]     = make_float4(rr[0], rr[1], rr[2], rr[3]);
    o[4 + r] = make_float4(ri[0], ri[1], ri[2], ri[3]);
}

__device__ inline void fill_proj(int p, float s, float pr[2][2], float pim[2][2])
{
    pr[0][0] = 0.5f; pr[0][1] = 0.f; pr[1][0] = 0.f; pr[1][1] = 0.5f;
    pim[0][0] = 0.f; pim[0][1] = 0.f; pim[1][0] = 0.f; pim[1][1] = 0.f;
    const float h = 0.5f * s;
    if (p == 0)      { pr[0][1] += h;  pr[1][0] += h; }   // sigma_x
    else if (p == 1) { pim[0][1] -= h; pim[1][0] += h; }  // sigma_y
    else             { pr[0][0] += h;  pr[1][1] -= h; }   // sigma_z
}

__device__ inline void fill_id(float pr[2][2], float pim[2][2])
{
    pr[0][0] = 1.f; pr[0][1] = 0.f; pr[1][0] = 0.f; pr[1][1] = 1.f;
    pim[0][0] = 0.f; pim[0][1] = 0.f; pim[1][0] = 0.f; pim[1][1] = 0.f;
}

// One block per batch element: reduce 128 trajectories -> rho_mean, compute 42
// measurement probabilities tr(M rho), clip, write [probs | input], then rho_mean.
__global__ __launch_bounds__(64) void reduce_meas_kernel(
    const float* __restrict__ ws,
    const float* __restrict__ inputs,
    float* __restrict__ out,
    int out_size)
{
    const int b = blockIdx.x;
    const int tid = threadIdx.x;
    __shared__ float sr[16], si[16];

    if (tid < 32) {
        const int plane = tid >> 4;
        const int e = tid & 15;
        float s = 0.f;
        for (int k = 0; k < NUM_TRAJ; k++)
            s += ws[((size_t)(k * BATCH + b)) * 32 + plane * 16 + e];
        s *= (1.0f / NUM_TRAJ);
        if (plane == 0) sr[e] = s; else si[e] = s;
    }
    __syncthreads();

    if (tid < 42) {
        float par[2][2], pai[2][2], pbr[2][2], pbi[2][2];
        const int m = tid;
        if (m < 36) {
            const int ia = m / 12, rem = m - ia * 12;
            const int ib = rem / 4, r2 = rem - ib * 4;
            fill_proj(ia, (r2 & 2) ? -1.f : 1.f, par, pai);
            fill_proj(ib, (r2 & 1) ? -1.f : 1.f, pbr, pbi);
        } else if (m < 39) {
            fill_proj(m - 36, 1.f, par, pai);
            fill_id(pbr, pbi);
        } else {
            fill_id(par, pai);
            fill_proj(m - 39, 1.f, pbr, pbi);
        }
        float prob = 0.f;
#pragma unroll
        for (int a1 = 0; a1 < 2; a1++)
#pragma unroll
            for (int b1 = 0; b1 < 2; b1++)
#pragma unroll
                for (int a2 = 0; a2 < 2; a2++)
#pragma unroll
                    for (int b2 = 0; b2 < 2; b2++) {
                        const int i = 2 * a1 + b1, j = 2 * a2 + b2;
                        const float Mr = par[a1][a2] * pbr[b1][b2] - pai[a1][a2] * pbi[b1][b2];
                        const float Mi = par[a1][a2] * pbi[b1][b2] + pai[a1][a2] * pbr[b1][b2];
                        prob += Mr * sr[j * 4 + i] - Mi * si[j * 4 + i];
                    }
        prob = fminf(fmaxf(prob, 0.f), 1.f);
        out[b * 43 + m] = prob;
    } else if (tid == 42) {
        out[b * 43 + 42] = inputs[b];
    }

    if (out_size >= 2752 + 2048) {
        if (tid < 16) {
            out[2752 + b * 32 + 2 * tid]     = sr[tid];
            out[2752 + b * 32 + 2 * tid + 1] = si[tid];
        }
    } else if (out_size >= 2752 + 1024) {
        if (tid < 16) out[2752 + b * 16 + tid] = sr[tid];
    }
}

extern "C" void kernel_launch(void* const* d_in, const int* in_sizes, int n_in,
                              void* d_out, int out_size, void* d_ws, size_t ws_size,
                              hipStream_t stream)
{
    const float* inputs = (const float*)d_in[0];
    const float* params = (const float*)d_in[1];
    const float* wvec   = (const float*)d_in[2];
    const float* rho0   = (const float*)d_in[3];
    const int rho0_cplx = (n_in > 3 && in_sizes[3] >= 32) ? 1 : 0;
    float* ws = (float*)d_ws;

    traj_kernel<<<(NTOT * 4) / 64, 64, 0, stream>>>(inputs, params, wvec, rho0, rho0_cplx, ws);
    reduce_meas_kernel<<<BATCH, 64, 0, stream>>>(ws, inputs, (float*)d_out, out_size);
}